// Round 1
// baseline (456.551 us; speedup 1.0000x reference)
//
#include <hip/hip_runtime.h>
#include <math.h>

#define LRELU_ALPHA 0.2f
#define NEG_INF -9.0e15f

constexpr int GN = 128;   // B*T
constexpr int NN = 512;   // nodes
constexpr int FD = 128;   // F_in == D == 128

// ---------------------------------------------------------------------------
// Pass 1: Wh = h @ W  (per g: 512x128 @ 128x128), fused e_src/e_dst = Wh @ a
// grid (128 g, 8 row-tiles), block 256. Tile 64 rows x 128 d, C = 8x4/thread.
// ---------------------------------------------------------------------------
__global__ __launch_bounds__(256) void wh_kernel(
    const float* __restrict__ h, const float* __restrict__ W,
    const float* __restrict__ a,
    float* __restrict__ Wh, float* __restrict__ esrc, float* __restrict__ edst)
{
    __shared__ float hl[64 * 32];    // 8 KB
    __shared__ float wl[32 * 128];   // 16 KB
    const int g   = blockIdx.x;
    const int i0  = blockIdx.y * 64;
    const int tid = threadIdx.x;
    const int tx  = tid & 31;        // d-group: d = tx*4 .. tx*4+3
    const int ty  = tid >> 5;        // row-group: rows ty*8 .. ty*8+7

    const float* hg = h + ((size_t)g * NN + i0) * FD;

    float C[8][4];
    #pragma unroll
    for (int r = 0; r < 8; ++r)
        #pragma unroll
        for (int c = 0; c < 4; ++c) C[r][c] = 0.f;

    for (int kc = 0; kc < 4; ++kc) {
        const int k0 = kc * 32;
        __syncthreads();
        for (int q = tid; q < 512; q += 256) {           // h tile 64x32
            int r = q >> 3, c4 = (q & 7) << 2;
            *(float4*)&hl[r * 32 + c4] = *(const float4*)&hg[r * FD + k0 + c4];
        }
        for (int q = tid; q < 1024; q += 256) {          // W tile 32x128
            int r = q >> 5, c4 = (q & 31) << 2;
            *(float4*)&wl[r * 128 + c4] = *(const float4*)&W[(k0 + r) * FD + c4];
        }
        __syncthreads();
        #pragma unroll
        for (int k = 0; k < 32; k += 4) {
            float bv[4][4];
            #pragma unroll
            for (int q = 0; q < 4; ++q) {
                float4 b4 = *(const float4*)&wl[(k + q) * 128 + tx * 4];
                bv[q][0] = b4.x; bv[q][1] = b4.y; bv[q][2] = b4.z; bv[q][3] = b4.w;
            }
            #pragma unroll
            for (int r = 0; r < 8; ++r) {
                float4 av = *(const float4*)&hl[(ty * 8 + r) * 32 + k];
                #pragma unroll
                for (int c = 0; c < 4; ++c)
                    C[r][c] += av.x * bv[0][c] + av.y * bv[1][c]
                             + av.z * bv[2][c] + av.w * bv[3][c];
            }
        }
    }

    const float4 as4 = *(const float4*)&a[tx * 4];
    const float4 ad4 = *(const float4*)&a[FD + tx * 4];
    #pragma unroll
    for (int r = 0; r < 8; ++r) {
        const int row = i0 + ty * 8 + r;
        *(float4*)&Wh[((size_t)g * NN + row) * FD + tx * 4] =
            make_float4(C[r][0], C[r][1], C[r][2], C[r][3]);
        float ps = C[r][0]*as4.x + C[r][1]*as4.y + C[r][2]*as4.z + C[r][3]*as4.w;
        float pd = C[r][0]*ad4.x + C[r][1]*ad4.y + C[r][2]*ad4.z + C[r][3]*ad4.w;
        #pragma unroll
        for (int off = 16; off >= 1; off >>= 1) {   // reduce over tx (bits 0..4)
            ps += __shfl_xor(ps, off);
            pd += __shfl_xor(pd, off);
        }
        if (tx == 0) {
            esrc[g * NN + row] = ps;
            edst[g * NN + row] = pd;
        }
    }
}

// ---------------------------------------------------------------------------
// Pass 2: masked softmax + att @ Wh, flash-style.
// grid (128 g, 8 row-tiles of 64), block 256.
// Phase A: per-row online (m, l); 4 lanes/row, shuffle-combined, kept in regs.
// Phase B: 8 chunks of 64 j: stage Wh chunk in LDS, build normalized P tile
//          (64x64) in LDS, accumulate 16 rows x 2 d per thread.
// LDS = 2 + 32 + 17 KB ~= 52 KB -> 3 blocks/CU.
// ---------------------------------------------------------------------------
__global__ __launch_bounds__(256) void attn_kernel(
    const float* __restrict__ Wh, const float* __restrict__ esrc,
    const float* __restrict__ edst, const int* __restrict__ adj,
    float* __restrict__ out)
{
    __shared__ float ed[NN];          // e_dst for this g
    __shared__ float whc[64 * 128];   // Wh chunk
    __shared__ float P[64][68];       // attention tile (padded stride)

    const int g   = blockIdx.x;
    const int i0  = blockIdx.y * 64;
    const int tid = threadIdx.x;

    ed[tid]       = edst[g * NN + tid];
    ed[tid + 256] = edst[g * NN + tid + 256];

    const int ia   = tid >> 2;        // local row 0..63
    const int sub  = tid & 3;         // 4 lanes per row
    const int rowA = i0 + ia;
    const float s  = esrc[g * NN + rowA];
    const int* adjrow = adj + rowA * NN;

    __syncthreads();

    // ---- Phase A: online softmax stats over all 512 j ----
    float m = -INFINITY, l = 0.f;
    for (int jj = 0; jj < 128; jj += 4) {
        const int j = sub * 128 + jj;
        const int4   av = *(const int4*)&adjrow[j];
        const float4 tv = *(const float4*)&ed[j];
        float x0 = s + tv.x; x0 = (x0 >= 0.f) ? x0 : LRELU_ALPHA * x0; x0 = (av.x > 0) ? x0 : NEG_INF;
        float x1 = s + tv.y; x1 = (x1 >= 0.f) ? x1 : LRELU_ALPHA * x1; x1 = (av.y > 0) ? x1 : NEG_INF;
        float x2 = s + tv.z; x2 = (x2 >= 0.f) ? x2 : LRELU_ALPHA * x2; x2 = (av.z > 0) ? x2 : NEG_INF;
        float x3 = s + tv.w; x3 = (x3 >= 0.f) ? x3 : LRELU_ALPHA * x3; x3 = (av.w > 0) ? x3 : NEG_INF;
        const float xq = fmaxf(fmaxf(x0, x1), fmaxf(x2, x3));
        const float xm = fmaxf(m, xq);
        l = l * __expf(m - xm) + __expf(x0 - xm) + __expf(x1 - xm)
                               + __expf(x2 - xm) + __expf(x3 - xm);
        m = xm;
    }
    #pragma unroll
    for (int off = 1; off <= 2; off <<= 1) {   // combine 4 sub-lanes
        const float m2 = __shfl_xor(m, off);
        const float l2 = __shfl_xor(l, off);
        const float nm = fmaxf(m, m2);
        l = l * __expf(m - nm) + l2 * __expf(m2 - nm);
        m = nm;
    }
    const float rl = 1.f / l;

    // ---- Phase B ----
    const int d2 = tid & 63;          // d = 2*d2, 2*d2+1
    const int ig = tid >> 6;          // row quarter: rows ig*16 .. ig*16+15
    float acc[16][2];
    #pragma unroll
    for (int r = 0; r < 16; ++r) { acc[r][0] = 0.f; acc[r][1] = 0.f; }

    const float* whg = Wh + (size_t)g * NN * FD;

    for (int jc = 0; jc < 8; ++jc) {
        const int j0 = jc * 64;
        __syncthreads();
        for (int q = tid; q < 2048; q += 256) {          // Wh chunk 64x128
            int r = q >> 5, c4 = (q & 31) << 2;
            *(float4*)&whc[r * 128 + c4] = *(const float4*)&whg[(j0 + r) * FD + c4];
        }
        #pragma unroll
        for (int qq = 0; qq < 16; qq += 4) {             // P tile: 16 cells/thread
            const int j = sub * 16 + qq;
            const int4   av = *(const int4*)&adjrow[j0 + j];
            const float4 tv = *(const float4*)&ed[j0 + j];
            float x0 = s + tv.x; x0 = (x0 >= 0.f) ? x0 : LRELU_ALPHA * x0; x0 = (av.x > 0) ? x0 : NEG_INF;
            float x1 = s + tv.y; x1 = (x1 >= 0.f) ? x1 : LRELU_ALPHA * x1; x1 = (av.y > 0) ? x1 : NEG_INF;
            float x2 = s + tv.z; x2 = (x2 >= 0.f) ? x2 : LRELU_ALPHA * x2; x2 = (av.z > 0) ? x2 : NEG_INF;
            float x3 = s + tv.w; x3 = (x3 >= 0.f) ? x3 : LRELU_ALPHA * x3; x3 = (av.w > 0) ? x3 : NEG_INF;
            float4 pv;
            pv.x = __expf(x0 - m) * rl;
            pv.y = __expf(x1 - m) * rl;
            pv.z = __expf(x2 - m) * rl;
            pv.w = __expf(x3 - m) * rl;
            *(float4*)&P[ia][j] = pv;
        }
        __syncthreads();
        #pragma unroll
        for (int j = 0; j < 64; j += 4) {
            const float2 w0 = *(const float2*)&whc[(j + 0) * 128 + d2 * 2];
            const float2 w1 = *(const float2*)&whc[(j + 1) * 128 + d2 * 2];
            const float2 w2 = *(const float2*)&whc[(j + 2) * 128 + d2 * 2];
            const float2 w3 = *(const float2*)&whc[(j + 3) * 128 + d2 * 2];
            #pragma unroll
            for (int r = 0; r < 16; ++r) {
                const float4 p = *(const float4*)&P[ig * 16 + r][j];
                acc[r][0] += p.x * w0.x + p.y * w1.x + p.z * w2.x + p.w * w3.x;
                acc[r][1] += p.x * w0.y + p.y * w1.y + p.z * w2.y + p.w * w3.y;
            }
        }
    }

    #pragma unroll
    for (int r = 0; r < 16; ++r) {
        const int row = i0 + ig * 16 + r;
        *(float2*)&out[((size_t)g * NN + row) * FD + d2 * 2] =
            make_float2(acc[r][0], acc[r][1]);
    }
}

// ---------------------------------------------------------------------------
extern "C" void kernel_launch(void* const* d_in, const int* in_sizes, int n_in,
                              void* d_out, int out_size, void* d_ws, size_t ws_size,
                              hipStream_t stream) {
    const float* h   = (const float*)d_in[0];
    const int*   adj = (const int*)d_in[1];
    const float* W   = (const float*)d_in[2];
    const float* a   = (const float*)d_in[3];
    float* out = (float*)d_out;

    // workspace: Wh (33.55 MB) + e_src (256 KB) + e_dst (256 KB)
    float* ws   = (float*)d_ws;
    float* Wh   = ws;
    float* esrc = ws + (size_t)GN * NN * FD;
    float* edst = esrc + GN * NN;

    wh_kernel<<<dim3(GN, 8), 256, 0, stream>>>(h, W, a, Wh, esrc, edst);
    attn_kernel<<<dim3(GN, 8), 256, 0, stream>>>(Wh, esrc, edst, adj, out);
}

// Round 2
// 152.333 us; speedup vs baseline: 2.9971x; 2.9971x over previous
//
#include <hip/hip_runtime.h>
#include <math.h>

typedef __attribute__((ext_vector_type(8))) short bf16x8;
typedef __attribute__((ext_vector_type(4))) float f32x4;

#define MFMA(a, b, c) __builtin_amdgcn_mfma_f32_16x16x32_bf16(a, b, c, 0, 0, 0)

constexpr int GN = 128;   // B*T
constexpr int NN = 512;   // nodes
constexpr int FD = 128;   // F_in == D == 128
#define LRELU(x) fmaxf((x), 0.2f * (x))
#define NEG_BIG -9.0e15f

__device__ inline unsigned short bf16_rne(float x) {
    unsigned u = __float_as_uint(x);
    unsigned r = u + 0x7fffu + ((u >> 16) & 1u);
    return (unsigned short)(r >> 16);
}
__device__ inline float bf16_to_f(unsigned short h) {
    return __uint_as_float(((unsigned)h) << 16);
}

// ---------------------------------------------------------------------------
// prep: blocks 0..31 build adjacency bitmask (512 rows x 16 words);
//       block 32 builds W (128x128) as bf16 hi/lo in MFMA-B-fragment swizzle:
//       elem (k,d) -> ((kk*8+nb)*64 + lane)*8 + idx,
//       kk=k>>5, nb=d>>4, lane=(d&15)+16*((k>>3)&3), idx=k&7
// ---------------------------------------------------------------------------
__global__ __launch_bounds__(256) void prep_kernel(
    const int* __restrict__ adj, const float* __restrict__ W,
    unsigned* __restrict__ mask, unsigned short* __restrict__ wsHi,
    unsigned short* __restrict__ wsLo)
{
    const int b = blockIdx.x, t = threadIdx.x;
    if (b < 32) {
        const int wi = b * 256 + t;           // word index 0..8191
        const int row = wi >> 4, wo = wi & 15;
        const int* p = adj + row * NN + wo * 32;
        unsigned m = 0;
        #pragma unroll
        for (int q = 0; q < 32; q += 4) {
            int4 v = *(const int4*)&p[q];
            m |= (v.x > 0 ? 1u : 0u) << q;
            m |= (v.y > 0 ? 1u : 0u) << (q + 1);
            m |= (v.z > 0 ? 1u : 0u) << (q + 2);
            m |= (v.w > 0 ? 1u : 0u) << (q + 3);
        }
        mask[wi] = m;
    } else {
        for (int q = 0; q < 64; ++q) {
            const int pos = t * 64 + q;
            const int idx = pos & 7, lane = (pos >> 3) & 63, cn = pos >> 9;
            const int kk = cn >> 3, nb = cn & 7;
            const int k = kk * 32 + ((lane >> 4) & 3) * 8 + idx;
            const int d = nb * 16 + (lane & 15);
            const float wv = W[k * FD + d];
            const unsigned short h = bf16_rne(wv);
            wsHi[pos] = h;
            wsLo[pos] = bf16_rne(wv - bf16_to_f(h));
        }
    }
}

// ---------------------------------------------------------------------------
// whb: per block (g, jt): Wh rows jt*128..+128 = h@W via 3-split bf16 MFMA.
// Outputs: esrc/edst (fp32), WhT as bf16 hi/lo in global B-fragment swizzle:
//   elem (j,d) of g at  g*65536 + ((KK*8+nb)*64 + lane)*8 + idx,
//   KK=j>>5, nb=d>>4, lane=(d&15)+16*((j>>3)&3), idx=j&7
// ---------------------------------------------------------------------------
__global__ __launch_bounds__(256, 2) void whb_kernel(
    const float* __restrict__ h, const float* __restrict__ a,
    const unsigned short* __restrict__ wsHi, const unsigned short* __restrict__ wsLo,
    unsigned short* __restrict__ whtHi, unsigned short* __restrict__ whtLo,
    float* __restrict__ esrc, float* __restrict__ edst)
{
    __shared__ __attribute__((aligned(16))) unsigned short sA[16384]; // W hi, then trans hi
    __shared__ __attribute__((aligned(16))) unsigned short sB[16384]; // W lo, then trans lo

    const int bid = blockIdx.x, g = bid >> 2, jt = bid & 3;
    const int t = threadIdx.x, lane = t & 63, w = t >> 6;
    const int q8 = (lane >> 4) * 8;

    for (int q = t; q < 2048; q += 256) {
        *(float4*)&sA[q * 8] = *(const float4*)&wsHi[q * 8];
        *(float4*)&sB[q * 8] = *(const float4*)&wsLo[q * 8];
    }
    __syncthreads();

    const int jw0 = jt * 128 + w * 32;                 // j base for this wave
    const float* hg = h + (size_t)(g * NN) * FD;

    f32x4 acc[2][8];
    #pragma unroll
    for (int mt = 0; mt < 2; ++mt)
        #pragma unroll
        for (int nb = 0; nb < 8; ++nb) acc[mt][nb] = (f32x4){0.f, 0.f, 0.f, 0.f};

    for (int kk = 0; kk < 4; ++kk) {
        bf16x8 ah[2], al[2];
        #pragma unroll
        for (int mt = 0; mt < 2; ++mt) {
            const float* src = hg + (jw0 + mt * 16 + (lane & 15)) * FD + kk * 32 + q8;
            const float4 x0 = *(const float4*)src;
            const float4 x1 = *(const float4*)(src + 4);
            const float xs[8] = {x0.x, x0.y, x0.z, x0.w, x1.x, x1.y, x1.z, x1.w};
            union { bf16x8 v; unsigned short u[8]; } H, L;
            #pragma unroll
            for (int i = 0; i < 8; ++i) {
                H.u[i] = bf16_rne(xs[i]);
                L.u[i] = bf16_rne(xs[i] - bf16_to_f(H.u[i]));
            }
            ah[mt] = H.v; al[mt] = L.v;
        }
        #pragma unroll
        for (int nb = 0; nb < 8; ++nb) {
            const bf16x8 bh = *(const bf16x8*)&sA[((kk * 8 + nb) * 64 + lane) * 8];
            const bf16x8 bl = *(const bf16x8*)&sB[((kk * 8 + nb) * 64 + lane) * 8];
            #pragma unroll
            for (int mt = 0; mt < 2; ++mt) {
                acc[mt][nb] = MFMA(al[mt], bh, acc[mt][nb]);
                acc[mt][nb] = MFMA(ah[mt], bl, acc[mt][nb]);
                acc[mt][nb] = MFMA(ah[mt], bh, acc[mt][nb]);
            }
        }
    }

    // ---- esrc / edst: per-row dot with a_src / a_dst, reduce over 16 lanes ----
    float av[8], bv[8];
    #pragma unroll
    for (int nb = 0; nb < 8; ++nb) {
        av[nb] = a[nb * 16 + (lane & 15)];
        bv[nb] = a[FD + nb * 16 + (lane & 15)];
    }
    #pragma unroll
    for (int mt = 0; mt < 2; ++mt)
        #pragma unroll
        for (int r = 0; r < 4; ++r) {
            float ps = 0.f, pd = 0.f;
            #pragma unroll
            for (int nb = 0; nb < 8; ++nb) {
                ps += acc[mt][nb][r] * av[nb];
                pd += acc[mt][nb][r] * bv[nb];
            }
            #pragma unroll
            for (int off = 1; off <= 8; off <<= 1) {
                ps += __shfl_xor(ps, off);
                pd += __shfl_xor(pd, off);
            }
            if ((lane & 15) == 0) {
                const int row = g * NN + jw0 + mt * 16 + (lane >> 4) * 4 + r;
                esrc[row] = ps;
                edst[row] = pd;
            }
        }

    // ---- transpose Wh -> swizzled bf16 hi/lo via LDS (reuse sA/sB) ----
    __syncthreads();
    #pragma unroll
    for (int mt = 0; mt < 2; ++mt) {
        const int lanep = (lane & 15) + 16 * (mt * 2 + (lane >> 5));
        const int ib = 4 * ((lane >> 4) & 1);
        #pragma unroll
        for (int nb = 0; nb < 8; ++nb) {
            const int off = ((w * 8 + nb) * 64 + lanep) * 8 + ib;  // ushort offset
            unsigned short h0 = bf16_rne(acc[mt][nb][0]);
            unsigned short h1 = bf16_rne(acc[mt][nb][1]);
            unsigned short h2 = bf16_rne(acc[mt][nb][2]);
            unsigned short h3 = bf16_rne(acc[mt][nb][3]);
            *(uint2*)&sA[off] = make_uint2((unsigned)h0 | ((unsigned)h1 << 16),
                                           (unsigned)h2 | ((unsigned)h3 << 16));
            unsigned short l0 = bf16_rne(acc[mt][nb][0] - bf16_to_f(h0));
            unsigned short l1 = bf16_rne(acc[mt][nb][1] - bf16_to_f(h1));
            unsigned short l2 = bf16_rne(acc[mt][nb][2] - bf16_to_f(h2));
            unsigned short l3 = bf16_rne(acc[mt][nb][3] - bf16_to_f(h3));
            *(uint2*)&sB[off] = make_uint2((unsigned)l0 | ((unsigned)l1 << 16),
                                           (unsigned)l2 | ((unsigned)l3 << 16));
        }
    }
    __syncthreads();
    const size_t gbase = (size_t)g * 65536 + (size_t)jt * 16384;
    for (int q = t; q < 2048; q += 256) {
        *(float4*)&whtHi[gbase + q * 8] = *(const float4*)&sA[q * 8];
        *(float4*)&whtLo[gbase + q * 8] = *(const float4*)&sB[q * 8];
    }
}

// ---------------------------------------------------------------------------
// attn: per block (g, it): rows i0..i0+128.  m-hat = lrelu(esrc + max(edst))
// (upper bound; softmax shift-invariant, masked -> exp(-9e15 - mhat) == 0).
// P fragments built in-register in MFMA A-layout, split hi/lo; l = sum p
// accumulated per lane and divided at the end.
// ---------------------------------------------------------------------------
__global__ __launch_bounds__(256, 2) void attn_kernel(
    const unsigned short* __restrict__ whtHi, const unsigned short* __restrict__ whtLo,
    const float* __restrict__ esrc, const float* __restrict__ edst,
    const unsigned* __restrict__ mask, float* __restrict__ out)
{
    __shared__ __attribute__((aligned(16))) float eds[NN];            // 2 KB
    __shared__ __attribute__((aligned(16))) unsigned maskS[2048];     // 8 KB
    __shared__ __attribute__((aligned(16))) unsigned short cHi[16384];// 32 KB
    __shared__ __attribute__((aligned(16))) unsigned short cLo[16384];// 32 KB
    __shared__ float redS[4];

    const int bid = blockIdx.x, g = bid >> 2, it = bid & 3;
    const int t = threadIdx.x, lane = t & 63, w = t >> 6;
    const int i0 = it * 128;
    const int q8 = (lane >> 4) * 8;

    const float e0 = edst[g * NN + t], e1 = edst[g * NN + 256 + t];
    eds[t] = e0; eds[t + 256] = e1;
    float mx = fmaxf(e0, e1);
    #pragma unroll
    for (int off = 1; off < 64; off <<= 1) mx = fmaxf(mx, __shfl_xor(mx, off));
    if (lane == 0) redS[w] = mx;
    *(uint4*)&maskS[t * 8]     = *(const uint4*)&mask[i0 * 16 + t * 8];
    *(uint4*)&maskS[t * 8 + 4] = *(const uint4*)&mask[i0 * 16 + t * 8 + 4];
    __syncthreads();
    const float maxE = fmaxf(fmaxf(redS[0], redS[1]), fmaxf(redS[2], redS[3]));

    const int rloc0 = w * 32 + (lane & 15);     // local row in [0,128)
    const int rloc1 = rloc0 + 16;
    const float s0 = esrc[g * NN + i0 + rloc0];
    const float s1 = esrc[g * NN + i0 + rloc1];
    const float mh0 = LRELU(s0 + maxE);
    const float mh1 = LRELU(s1 + maxE);

    f32x4 acc[2][8];
    #pragma unroll
    for (int mt = 0; mt < 2; ++mt)
        #pragma unroll
        for (int nb = 0; nb < 8; ++nb) acc[mt][nb] = (f32x4){0.f, 0.f, 0.f, 0.f};
    float lsum0 = 0.f, lsum1 = 0.f;

    for (int c = 0; c < 4; ++c) {
        __syncthreads();
        const size_t gb = (size_t)g * 65536 + (size_t)c * 16384;
        for (int q = t; q < 2048; q += 256) {
            *(float4*)&cHi[q * 8] = *(const float4*)&whtHi[gb + q * 8];
            *(float4*)&cLo[q * 8] = *(const float4*)&whtLo[gb + q * 8];
        }
        __syncthreads();
        #pragma unroll
        for (int kl = 0; kl < 4; ++kl) {
            const int kk = c * 4 + kl;
            const float* ep = &eds[kk * 32 + q8];
            const float4 ed0 = *(const float4*)ep;
            const float4 ed1 = *(const float4*)(ep + 4);
            const float ev[8] = {ed0.x, ed0.y, ed0.z, ed0.w, ed1.x, ed1.y, ed1.z, ed1.w};
            const unsigned mw0 = maskS[rloc0 * 16 + kk] >> q8;
            const unsigned mw1 = maskS[rloc1 * 16 + kk] >> q8;

            union { bf16x8 v; unsigned short u[8]; } H0, L0, H1, L1;
            #pragma unroll
            for (int i = 0; i < 8; ++i) {
                float x = s0 + ev[i];
                x = LRELU(x);
                x = ((mw0 >> i) & 1u) ? x : NEG_BIG;
                const float p = __expf(x - mh0);
                lsum0 += p;
                const unsigned short ph = bf16_rne(p);
                H0.u[i] = ph;
                L0.u[i] = bf16_rne(p - bf16_to_f(ph));
            }
            #pragma unroll
            for (int i = 0; i < 8; ++i) {
                float x = s1 + ev[i];
                x = LRELU(x);
                x = ((mw1 >> i) & 1u) ? x : NEG_BIG;
                const float p = __expf(x - mh1);
                lsum1 += p;
                const unsigned short ph = bf16_rne(p);
                H1.u[i] = ph;
                L1.u[i] = bf16_rne(p - bf16_to_f(ph));
            }
            #pragma unroll
            for (int nb = 0; nb < 8; ++nb) {
                const bf16x8 bh = *(const bf16x8*)&cHi[((kl * 8 + nb) * 64 + lane) * 8];
                const bf16x8 bl = *(const bf16x8*)&cLo[((kl * 8 + nb) * 64 + lane) * 8];
                acc[0][nb] = MFMA(L0.v, bh, acc[0][nb]);
                acc[0][nb] = MFMA(H0.v, bl, acc[0][nb]);
                acc[0][nb] = MFMA(H0.v, bh, acc[0][nb]);
                acc[1][nb] = MFMA(L1.v, bh, acc[1][nb]);
                acc[1][nb] = MFMA(H1.v, bl, acc[1][nb]);
                acc[1][nb] = MFMA(H1.v, bh, acc[1][nb]);
            }
        }
    }

    lsum0 += __shfl_xor(lsum0, 16); lsum0 += __shfl_xor(lsum0, 32);
    lsum1 += __shfl_xor(lsum1, 16); lsum1 += __shfl_xor(lsum1, 32);

    #pragma unroll
    for (int r = 0; r < 4; ++r) {
        const int rr = (lane >> 4) * 4 + r;            // row within 16-tile
        const float rl0 = 1.0f / __shfl(lsum0, rr);
        const float rl1 = 1.0f / __shfl(lsum1, rr);
        const int row0 = g * NN + i0 + w * 32 + rr;
        const int row1 = row0 + 16;
        #pragma unroll
        for (int nb = 0; nb < 8; ++nb) {
            out[row0 * FD + nb * 16 + (lane & 15)] = acc[0][nb][r] * rl0;
            out[row1 * FD + nb * 16 + (lane & 15)] = acc[1][nb][r] * rl1;
        }
    }
}

// ---------------------------------------------------------------------------
extern "C" void kernel_launch(void* const* d_in, const int* in_sizes, int n_in,
                              void* d_out, int out_size, void* d_ws, size_t ws_size,
                              hipStream_t stream) {
    const float* h   = (const float*)d_in[0];
    const int*   adj = (const int*)d_in[1];
    const float* W   = (const float*)d_in[2];
    const float* a   = (const float*)d_in[3];
    float* out = (float*)d_out;

    // workspace carve-up (~34.2 MB)
    unsigned short* whtHi = (unsigned short*)d_ws;                       // 16.78 MB
    unsigned short* whtLo = whtHi + (size_t)GN * 65536;                  // 16.78 MB
    float* esrc = (float*)(whtLo + (size_t)GN * 65536);                  // 256 KB
    float* edst = esrc + GN * NN;                                        // 256 KB
    unsigned* mask = (unsigned*)(edst + GN * NN);                        // 32 KB
    unsigned short* wsHi = (unsigned short*)(mask + 8192);               // 32 KB
    unsigned short* wsLo = wsHi + 16384;                                 // 32 KB

    prep_kernel<<<33, 256, 0, stream>>>(adj, W, mask, wsHi, wsLo);
    whb_kernel<<<512, 256, 0, stream>>>(h, a, wsHi, wsLo, whtHi, whtLo, esrc, edst);
    attn_kernel<<<512, 256, 0, stream>>>(whtHi, whtLo, esrc, edst, mask, out);
}

// Round 3
// 132.820 us; speedup vs baseline: 3.4374x; 1.1469x over previous
//
#include <hip/hip_runtime.h>
#include <math.h>

typedef __attribute__((ext_vector_type(8))) short bf16x8;
typedef __attribute__((ext_vector_type(4))) float f32x4;

#define MFMA(a, b, c) __builtin_amdgcn_mfma_f32_16x16x32_bf16(a, b, c, 0, 0, 0)

constexpr int GN = 128;   // B*T
constexpr int NN = 512;   // nodes
constexpr int FD = 128;   // F_in == D == 128
#define LRELU(x) fmaxf((x), 0.2f * (x))
#define NEG_BIG -9.0e15f

__device__ inline unsigned short bf16_rne(float x) {
    unsigned u = __float_as_uint(x);
    unsigned r = u + 0x7fffu + ((u >> 16) & 1u);
    return (unsigned short)(r >> 16);
}
__device__ inline float bf16_to_f(unsigned short h) {
    return __uint_as_float(((unsigned)h) << 16);
}
// round-to-nearest-even bf16 kept in the TOP 16 bits of a u32
__device__ inline unsigned rne_top16(float x) {
    unsigned u = __float_as_uint(x);
    return u + 0x7fffu + ((u >> 16) & 1u);
}
// pack top-16 of e0 (-> low half) and e1 (-> high half)
__device__ inline unsigned pack_top16(unsigned e1, unsigned e0) {
    return __builtin_amdgcn_perm(e1, e0, 0x07060302u);
}
// async global->LDS, 16 bytes per lane
__device__ inline void gload16(const void* g, void* l) {
    __builtin_amdgcn_global_load_lds(
        (const __attribute__((address_space(1))) unsigned*)g,
        (__attribute__((address_space(3))) unsigned*)l, 16, 0, 0);
}
// XCD-aware swizzle: 4 blocks sharing one g land on the same XCD (bid%8)
__device__ inline void decode_bid(int bid, int& g, int& tile) {
    const int xcd = bid & 7, slot = bid >> 3;
    g = xcd + 8 * (slot >> 2);
    tile = slot & 3;
}

// ---------------------------------------------------------------------------
// prep: blocks 0..31 adjacency bitmask (512 rows x 16 words);
//       blocks 32..63 W as bf16 hi(trunc)/lo(rne) in MFMA-B-fragment swizzle:
//       elem (k,d) -> ((kk*8+nb)*64 + lane)*8 + idx,
//       kk=k>>5, nb=d>>4, lane=(d&15)+16*((k>>3)&3), idx=k&7
// ---------------------------------------------------------------------------
__global__ __launch_bounds__(256) void prep_kernel(
    const int* __restrict__ adj, const float* __restrict__ W,
    unsigned* __restrict__ mask, unsigned short* __restrict__ wsHi,
    unsigned short* __restrict__ wsLo)
{
    const int b = blockIdx.x, t = threadIdx.x;
    if (b < 32) {
        const int wi = b * 256 + t;           // word index 0..8191
        const int row = wi >> 4, wo = wi & 15;
        const int* p = adj + row * NN + wo * 32;
        unsigned m = 0;
        #pragma unroll
        for (int q = 0; q < 32; q += 4) {
            int4 v = *(const int4*)&p[q];
            m |= (v.x > 0 ? 1u : 0u) << q;
            m |= (v.y > 0 ? 1u : 0u) << (q + 1);
            m |= (v.z > 0 ? 1u : 0u) << (q + 2);
            m |= (v.w > 0 ? 1u : 0u) << (q + 3);
        }
        mask[wi] = m;
    } else {
        const int base = (b - 32) * 512 + t * 2;
        #pragma unroll
        for (int q = 0; q < 2; ++q) {
            const int pos = base + q;
            const int idx = pos & 7, lane = (pos >> 3) & 63, cn = pos >> 9;
            const int kk = cn >> 3, nb = cn & 7;
            const int k = kk * 32 + ((lane >> 4) & 3) * 8 + idx;
            const int d = nb * 16 + (lane & 15);
            const float wv = W[k * FD + d];
            const unsigned u = __float_as_uint(wv);
            wsHi[pos] = (unsigned short)(u >> 16);                 // truncate
            wsLo[pos] = (unsigned short)(rne_top16(
                            wv - __uint_as_float(u & 0xffff0000u)) >> 16);
        }
    }
}

// ---------------------------------------------------------------------------
// whb: block (g, jt): Wh rows jt*128..+128 = h@W via 3-split bf16 MFMA.
// Per kk: stage W slice (8+8 KB) and h tile (16 KB, pre-arranged in MFMA
// A-fragment order) via global_load_lds; conflict-free ds_read_b128.
// Outputs: esrc/edst fp32; WhT bf16 hi/lo in global B-fragment swizzle.
// LDS 32 KB -> high occupancy.
// ---------------------------------------------------------------------------
__global__ __launch_bounds__(256, 3) void whb_kernel(
    const float* __restrict__ h, const float* __restrict__ a,
    const unsigned short* __restrict__ wsHi, const unsigned short* __restrict__ wsLo,
    unsigned short* __restrict__ whtHi, unsigned short* __restrict__ whtLo,
    float* __restrict__ esrc, float* __restrict__ edst)
{
    __shared__ __attribute__((aligned(16))) unsigned short sBuf[16384]; // 32 KB
    unsigned short* sWhi = sBuf;                 // 4096 shorts (8 KB)
    unsigned short* sWlo = sBuf + 4096;          // 8 KB
    float* hs = (float*)(sBuf + 8192);           // 4096 floats (16 KB)

    int g, jt;
    decode_bid(blockIdx.x, g, jt);
    const int t = threadIdx.x, lane = t & 63, w = t >> 6;
    const int i0r = jt * 128;
    const float* hg = h + (size_t)(g * NN) * FD;

    f32x4 acc[2][8];
    #pragma unroll
    for (int mt = 0; mt < 2; ++mt)
        #pragma unroll
        for (int nb = 0; nb < 8; ++nb) acc[mt][nb] = (f32x4){0.f, 0.f, 0.f, 0.f};

    for (int kk = 0; kk < 4; ++kk) {
        __syncthreads();
        // W slice, B-frag order, contiguous
        for (int q = t; q < 512; q += 256) {
            gload16(&wsHi[kk * 4096 + q * 8], &sWhi[q * 8]);
            gload16(&wsLo[kk * 4096 + q * 8], &sWlo[q * 8]);
        }
        // h tile in A-frag order: slot q -> (w2,mt,lane',half)
        for (int q = t; q < 1024; q += 256) {
            const int w2 = q >> 8, mt = (q >> 7) & 1;
            const int lp = (q >> 1) & 63, half = q & 1;
            const int row = i0r + w2 * 32 + mt * 16 + (lp & 15);
            const int k = kk * 32 + ((lp >> 4) & 3) * 8 + half * 4;
            gload16(hg + (size_t)row * FD + k, &hs[q * 4]);
        }
        __syncthreads();

        bf16x8 ah[2], al[2];
        #pragma unroll
        for (int mt = 0; mt < 2; ++mt) {
            const float* fb = &hs[((w * 2 + mt) * 64 + lane) * 8];
            const float4 f0 = *(const float4*)fb;
            const float4 f1 = *(const float4*)(fb + 4);
            const float xs[8] = {f0.x, f0.y, f0.z, f0.w, f1.x, f1.y, f1.z, f1.w};
            union { bf16x8 v; unsigned u[4]; } H, L;
            #pragma unroll
            for (int j = 0; j < 4; ++j) {
                const unsigned e0 = __float_as_uint(xs[2 * j]);
                const unsigned e1 = __float_as_uint(xs[2 * j + 1]);
                H.u[j] = pack_top16(e1, e0);
                const unsigned l0 = rne_top16(xs[2*j]   - __uint_as_float(e0 & 0xffff0000u));
                const unsigned l1 = rne_top16(xs[2*j+1] - __uint_as_float(e1 & 0xffff0000u));
                L.u[j] = pack_top16(l1, l0);
            }
            ah[mt] = H.v; al[mt] = L.v;
        }
        #pragma unroll
        for (int nb = 0; nb < 8; ++nb) {
            const bf16x8 bh = *(const bf16x8*)&sWhi[(nb * 64 + lane) * 8];
            const bf16x8 bl = *(const bf16x8*)&sWlo[(nb * 64 + lane) * 8];
            #pragma unroll
            for (int mt = 0; mt < 2; ++mt) {
                acc[mt][nb] = MFMA(al[mt], bh, acc[mt][nb]);
                acc[mt][nb] = MFMA(ah[mt], bl, acc[mt][nb]);
                acc[mt][nb] = MFMA(ah[mt], bh, acc[mt][nb]);
            }
        }
    }

    // ---- esrc / edst: per-row dot with a_src / a_dst, reduce over 16 lanes ----
    float av[8], bv[8];
    #pragma unroll
    for (int nb = 0; nb < 8; ++nb) {
        av[nb] = a[nb * 16 + (lane & 15)];
        bv[nb] = a[FD + nb * 16 + (lane & 15)];
    }
    #pragma unroll
    for (int mt = 0; mt < 2; ++mt)
        #pragma unroll
        for (int r = 0; r < 4; ++r) {
            float ps = 0.f, pd = 0.f;
            #pragma unroll
            for (int nb = 0; nb < 8; ++nb) {
                ps += acc[mt][nb][r] * av[nb];
                pd += acc[mt][nb][r] * bv[nb];
            }
            #pragma unroll
            for (int off = 1; off <= 8; off <<= 1) {
                ps += __shfl_xor(ps, off);
                pd += __shfl_xor(pd, off);
            }
            if ((lane & 15) == 0) {
                const int row = g * NN + i0r + w * 32 + mt * 16 + (lane >> 4) * 4 + r;
                esrc[row] = ps;
                edst[row] = pd;
            }
        }

    // ---- transpose Wh -> swizzled bf16 hi/lo, two 4-nb passes (32 KB LDS) ----
    unsigned short* sTh = sBuf;          // 8192 shorts
    unsigned short* sTl = sBuf + 8192;   // 8192 shorts
    const size_t gbase = (size_t)g * 65536 + (size_t)jt * 16384;
    const int lanep = (lane & 15) + 16 * ((lane >> 5) + 0);  // + mt*32 added below? no:
    // lanep depends on mt: (lane&15) + 16*(mt*2 + (lane>>5))
    const int ib = 4 * ((lane >> 4) & 1);

    for (int ph = 0; ph < 2; ++ph) {
        __syncthreads();
        #pragma unroll
        for (int mt = 0; mt < 2; ++mt) {
            const int lp2 = (lane & 15) + 16 * (mt * 2 + (lane >> 5));
            #pragma unroll
            for (int nbp = 0; nbp < 4; ++nbp) {
                const int nb = ph * 4 + nbp;
                const int off = ((w * 4 + nbp) * 64 + lp2) * 8 + ib;
                const unsigned u0 = __float_as_uint(acc[mt][nb][0]);
                const unsigned u1 = __float_as_uint(acc[mt][nb][1]);
                const unsigned u2 = __float_as_uint(acc[mt][nb][2]);
                const unsigned u3 = __float_as_uint(acc[mt][nb][3]);
                *(uint2*)&sTh[off] = make_uint2(pack_top16(u1, u0), pack_top16(u3, u2));
                const unsigned l0 = rne_top16(acc[mt][nb][0] - __uint_as_float(u0 & 0xffff0000u));
                const unsigned l1 = rne_top16(acc[mt][nb][1] - __uint_as_float(u1 & 0xffff0000u));
                const unsigned l2 = rne_top16(acc[mt][nb][2] - __uint_as_float(u2 & 0xffff0000u));
                const unsigned l3 = rne_top16(acc[mt][nb][3] - __uint_as_float(u3 & 0xffff0000u));
                *(uint2*)&sTl[off] = make_uint2(pack_top16(l1, l0), pack_top16(l3, l2));
            }
        }
        __syncthreads();
        for (int q = t; q < 1024; q += 256) {
            const int qw = q >> 8, qr = q & 255;
            const size_t go = gbase + (size_t)(qw * 8 + ph * 4) * 512 + qr * 8;
            *(float4*)&whtHi[go] = *(const float4*)&sTh[q * 8];
            *(float4*)&whtLo[go] = *(const float4*)&sTl[q * 8];
        }
    }
    (void)lanep;
}

// ---------------------------------------------------------------------------
// attn: block (g, it): 128 rows. m-hat = lrelu(esrc + max(edst)) upper bound
// (softmax shift-invariant; masked -> exp(-9e15 - mhat) == 0 exactly).
// 8 chunks of 64 j; WhT chunks staged via global_load_lds; P fragments built
// in-register (truncation hi + rne lo, v_perm packing); l = per-lane sum.
// LDS 43 KB -> 3 blocks/CU.
// ---------------------------------------------------------------------------
__global__ __launch_bounds__(256, 3) void attn_kernel(
    const unsigned short* __restrict__ whtHi, const unsigned short* __restrict__ whtLo,
    const float* __restrict__ esrc, const float* __restrict__ edst,
    const unsigned* __restrict__ mask, float* __restrict__ out)
{
    __shared__ __attribute__((aligned(16))) float eds[NN];            // 2 KB
    __shared__ __attribute__((aligned(16))) unsigned maskS[2048];     // 8 KB
    __shared__ __attribute__((aligned(16))) unsigned short cHi[8192]; // 16 KB
    __shared__ __attribute__((aligned(16))) unsigned short cLo[8192]; // 16 KB
    __shared__ float redS[4];

    int g, it;
    decode_bid(blockIdx.x, g, it);
    const int t = threadIdx.x, lane = t & 63, w = t >> 6;
    const int i0 = it * 128;
    const int q8 = (lane >> 4) * 8;

    const float e0 = edst[g * NN + t], e1 = edst[g * NN + 256 + t];
    eds[t] = e0; eds[t + 256] = e1;
    float mx = fmaxf(e0, e1);
    #pragma unroll
    for (int off = 1; off < 64; off <<= 1) mx = fmaxf(mx, __shfl_xor(mx, off));
    if (lane == 0) redS[w] = mx;
    *(uint4*)&maskS[t * 8]     = *(const uint4*)&mask[i0 * 16 + t * 8];
    *(uint4*)&maskS[t * 8 + 4] = *(const uint4*)&mask[i0 * 16 + t * 8 + 4];
    __syncthreads();
    const float maxE = fmaxf(fmaxf(redS[0], redS[1]), fmaxf(redS[2], redS[3]));

    const int rloc0 = w * 32 + (lane & 15);     // local row in [0,128)
    const int rloc1 = rloc0 + 16;
    const float s0 = esrc[g * NN + i0 + rloc0];
    const float s1 = esrc[g * NN + i0 + rloc1];
    const float mh0 = LRELU(s0 + maxE);
    const float mh1 = LRELU(s1 + maxE);

    f32x4 acc[2][8];
    #pragma unroll
    for (int mt = 0; mt < 2; ++mt)
        #pragma unroll
        for (int nb = 0; nb < 8; ++nb) acc[mt][nb] = (f32x4){0.f, 0.f, 0.f, 0.f};
    float lsum0 = 0.f, lsum1 = 0.f;

    for (int c2 = 0; c2 < 8; ++c2) {
        __syncthreads();
        const size_t gb = (size_t)g * 65536 + (size_t)c2 * 8192;   // shorts
        for (int q = t; q < 1024; q += 256) {
            gload16(&whtHi[gb + q * 8], &cHi[q * 8]);
            gload16(&whtLo[gb + q * 8], &cLo[q * 8]);
        }
        __syncthreads();
        #pragma unroll
        for (int kl = 0; kl < 2; ++kl) {
            const int kk = c2 * 2 + kl;
            const float* ep = &eds[kk * 32 + q8];
            const float4 ed0 = *(const float4*)ep;
            const float4 ed1 = *(const float4*)(ep + 4);
            const float ev[8] = {ed0.x, ed0.y, ed0.z, ed0.w, ed1.x, ed1.y, ed1.z, ed1.w};
            const unsigned mw0 = maskS[rloc0 * 16 + kk] >> q8;
            const unsigned mw1 = maskS[rloc1 * 16 + kk] >> q8;

            union { bf16x8 v; unsigned u[4]; } H0, L0, H1, L1;
            unsigned uh[8], ul[8];
            #pragma unroll
            for (int i = 0; i < 8; ++i) {
                float x = s0 + ev[i];
                x = LRELU(x);
                x = ((mw0 >> i) & 1u) ? x : NEG_BIG;
                const float p = __expf(x - mh0);
                lsum0 += p;
                const unsigned u = __float_as_uint(p);
                uh[i] = u;
                ul[i] = rne_top16(p - __uint_as_float(u & 0xffff0000u));
            }
            #pragma unroll
            for (int j = 0; j < 4; ++j) {
                H0.u[j] = pack_top16(uh[2*j+1], uh[2*j]);
                L0.u[j] = pack_top16(ul[2*j+1], ul[2*j]);
            }
            #pragma unroll
            for (int i = 0; i < 8; ++i) {
                float x = s1 + ev[i];
                x = LRELU(x);
                x = ((mw1 >> i) & 1u) ? x : NEG_BIG;
                const float p = __expf(x - mh1);
                lsum1 += p;
                const unsigned u = __float_as_uint(p);
                uh[i] = u;
                ul[i] = rne_top16(p - __uint_as_float(u & 0xffff0000u));
            }
            #pragma unroll
            for (int j = 0; j < 4; ++j) {
                H1.u[j] = pack_top16(uh[2*j+1], uh[2*j]);
                L1.u[j] = pack_top16(ul[2*j+1], ul[2*j]);
            }
            #pragma unroll
            for (int nb = 0; nb < 8; ++nb) {
                const bf16x8 bh = *(const bf16x8*)&cHi[((kl * 8 + nb) * 64 + lane) * 8];
                const bf16x8 bl = *(const bf16x8*)&cLo[((kl * 8 + nb) * 64 + lane) * 8];
                acc[0][nb] = MFMA(L0.v, bh, acc[0][nb]);
                acc[0][nb] = MFMA(H0.v, bl, acc[0][nb]);
                acc[0][nb] = MFMA(H0.v, bh, acc[0][nb]);
                acc[1][nb] = MFMA(L1.v, bh, acc[1][nb]);
                acc[1][nb] = MFMA(H1.v, bl, acc[1][nb]);
                acc[1][nb] = MFMA(H1.v, bh, acc[1][nb]);
            }
        }
    }

    lsum0 += __shfl_xor(lsum0, 16); lsum0 += __shfl_xor(lsum0, 32);
    lsum1 += __shfl_xor(lsum1, 16); lsum1 += __shfl_xor(lsum1, 32);

    #pragma unroll
    for (int r = 0; r < 4; ++r) {
        const int rr = (lane >> 4) * 4 + r;            // row within 16-tile
        const float rl0 = 1.0f / __shfl(lsum0, rr);
        const float rl1 = 1.0f / __shfl(lsum1, rr);
        const int row0 = g * NN + i0 + w * 32 + rr;
        const int row1 = row0 + 16;
        #pragma unroll
        for (int nb = 0; nb < 8; ++nb) {
            out[row0 * FD + nb * 16 + (lane & 15)] = acc[0][nb][r] * rl0;
            out[row1 * FD + nb * 16 + (lane & 15)] = acc[1][nb][r] * rl1;
        }
    }
}

// ---------------------------------------------------------------------------
extern "C" void kernel_launch(void* const* d_in, const int* in_sizes, int n_in,
                              void* d_out, int out_size, void* d_ws, size_t ws_size,
                              hipStream_t stream) {
    const float* h   = (const float*)d_in[0];
    const int*   adj = (const int*)d_in[1];
    const float* W   = (const float*)d_in[2];
    const float* a   = (const float*)d_in[3];
    float* out = (float*)d_out;

    unsigned short* whtHi = (unsigned short*)d_ws;                       // 16.78 MB
    unsigned short* whtLo = whtHi + (size_t)GN * 65536;                  // 16.78 MB
    float* esrc = (float*)(whtLo + (size_t)GN * 65536);                  // 256 KB
    float* edst = esrc + GN * NN;                                        // 256 KB
    unsigned* mask = (unsigned*)(edst + GN * NN);                        // 32 KB
    unsigned short* wsHi = (unsigned short*)(mask + 8192);               // 32 KB
    unsigned short* wsLo = wsHi + 16384;                                 // 32 KB

    prep_kernel<<<64, 256, 0, stream>>>(adj, W, mask, wsHi, wsLo);
    whb_kernel<<<512, 256, 0, stream>>>(h, a, wsHi, wsLo, whtHi, whtLo, esrc, edst);
    attn_kernel<<<512, 256, 0, stream>>>(whtHi, whtLo, esrc, edst, mask, out);
}

// Round 4
// 130.738 us; speedup vs baseline: 3.4921x; 1.0159x over previous
//
#include <hip/hip_runtime.h>
#include <math.h>

typedef __attribute__((ext_vector_type(8))) short bf16x8;
typedef __attribute__((ext_vector_type(4))) float f32x4;

#define MFMA(a, b, c) __builtin_amdgcn_mfma_f32_16x16x32_bf16(a, b, c, 0, 0, 0)

constexpr int GN = 128;   // B*T
constexpr int NN = 512;   // nodes
constexpr int FD = 128;   // F_in == D == 128
#define LRELU(x) fmaxf((x), 0.2f * (x))
#define NEG_BIG -9.0e15f

// round-to-nearest-even bf16 kept in the TOP 16 bits of a u32
__device__ inline unsigned rne_top16(float x) {
    unsigned u = __float_as_uint(x);
    return u + 0x7fffu + ((u >> 16) & 1u);
}
// pack top-16 of e0 (-> low half) and e1 (-> high half)
__device__ inline unsigned pack_top16(unsigned e1, unsigned e0) {
    return __builtin_amdgcn_perm(e1, e0, 0x07060302u);
}
// async global->LDS, 16 bytes per lane
__device__ inline void gload16(const void* g, void* l) {
    __builtin_amdgcn_global_load_lds(
        (const __attribute__((address_space(1))) unsigned*)g,
        (__attribute__((address_space(3))) unsigned*)l, 16, 0, 0);
}

// ---------------------------------------------------------------------------
// prep: blocks 0..31 adjacency bitmask (512 rows x 16 words);
//       blocks 32..63 W as bf16 hi(trunc)/lo(rne) in MFMA-B-fragment swizzle:
//       elem (k,d) -> ((kk*8+nb)*64 + lane)*8 + idx,
//       kk=k>>5, nb=d>>4, lane=(d&15)+16*((k>>3)&3), idx=k&7
// ---------------------------------------------------------------------------
__global__ __launch_bounds__(256) void prep_kernel(
    const int* __restrict__ adj, const float* __restrict__ W,
    unsigned* __restrict__ mask, unsigned short* __restrict__ wsHi,
    unsigned short* __restrict__ wsLo)
{
    const int b = blockIdx.x, t = threadIdx.x;
    if (b < 32) {
        const int wi = b * 256 + t;           // word index 0..8191
        const int row = wi >> 4, wo = wi & 15;
        const int* p = adj + row * NN + wo * 32;
        unsigned m = 0;
        #pragma unroll
        for (int q = 0; q < 32; q += 4) {
            int4 v = *(const int4*)&p[q];
            m |= (v.x > 0 ? 1u : 0u) << q;
            m |= (v.y > 0 ? 1u : 0u) << (q + 1);
            m |= (v.z > 0 ? 1u : 0u) << (q + 2);
            m |= (v.w > 0 ? 1u : 0u) << (q + 3);
        }
        mask[wi] = m;
    } else {
        const int base = (b - 32) * 512 + t * 2;
        #pragma unroll
        for (int q = 0; q < 2; ++q) {
            const int pos = base + q;
            const int idx = pos & 7, lane = (pos >> 3) & 63, cn = pos >> 9;
            const int kk = cn >> 3, nb = cn & 7;
            const int k = kk * 32 + ((lane >> 4) & 3) * 8 + idx;
            const int d = nb * 16 + (lane & 15);
            const float wv = W[k * FD + d];
            const unsigned u = __float_as_uint(wv);
            wsHi[pos] = (unsigned short)(u >> 16);                 // truncate
            wsLo[pos] = (unsigned short)(rne_top16(
                            wv - __uint_as_float(u & 0xffff0000u)) >> 16);
        }
    }
}

// ---------------------------------------------------------------------------
// whb: block (g, jt): Wh rows jt*128..+128 = h@W via 3-split bf16 MFMA.
// W (hi+lo, 64 KB) staged ONCE via global_load_lds; h read straight into
// registers (lanes l,l+16,l+32,l+48 cover one 128B line -> coalesced).
// K-loop has NO barriers. Outputs: esrc/edst fp32; WhT bf16 hi/lo in global
// B-fragment swizzle (elem (j,d): ((KK*8+nb)*64 + lanep)*8 + idx, KK=j>>5,
// nb=d>>4, lanep=(d&15)+16*((j>>3)&3), idx=j&7).
// ---------------------------------------------------------------------------
__global__ __launch_bounds__(256, 2) void whb_kernel(
    const float* __restrict__ h, const float* __restrict__ a,
    const unsigned short* __restrict__ wsHi, const unsigned short* __restrict__ wsLo,
    unsigned short* __restrict__ whtHi, unsigned short* __restrict__ whtLo,
    float* __restrict__ esrc, float* __restrict__ edst)
{
    __shared__ __attribute__((aligned(16))) unsigned short sW[32768]; // 64 KB

    const int bid = blockIdx.x;
    const int xcd = bid & 7, slot = bid >> 3;
    const int g = xcd + 8 * (slot >> 2);
    const int jt = slot & 3;
    const int t = threadIdx.x, lane = t & 63, w = t >> 6;
    const int i0r = jt * 128;
    const int q8 = (lane >> 4) * 8;
    const float* hg = h + (size_t)(g * NN) * FD;

    for (int q = t; q < 2048; q += 256) {
        gload16(&wsHi[q * 8], &sW[q * 8]);
        gload16(&wsLo[q * 8], &sW[16384 + q * 8]);
    }
    __syncthreads();

    f32x4 acc[2][8];
    #pragma unroll
    for (int mt = 0; mt < 2; ++mt)
        #pragma unroll
        for (int nb = 0; nb < 8; ++nb) acc[mt][nb] = (f32x4){0.f, 0.f, 0.f, 0.f};

    #pragma unroll
    for (int kk = 0; kk < 4; ++kk) {
        bf16x8 ah[2], al[2];
        #pragma unroll
        for (int mt = 0; mt < 2; ++mt) {
            const float* src = hg + (size_t)(i0r + w * 32 + mt * 16 + (lane & 15)) * FD
                             + kk * 32 + q8;
            const float4 f0 = *(const float4*)src;
            const float4 f1 = *(const float4*)(src + 4);
            const float xs[8] = {f0.x, f0.y, f0.z, f0.w, f1.x, f1.y, f1.z, f1.w};
            union { bf16x8 v; unsigned u[4]; } H, L;
            #pragma unroll
            for (int j = 0; j < 4; ++j) {
                const unsigned e0 = __float_as_uint(xs[2 * j]);
                const unsigned e1 = __float_as_uint(xs[2 * j + 1]);
                H.u[j] = pack_top16(e1, e0);
                const unsigned l0 = rne_top16(xs[2*j]   - __uint_as_float(e0 & 0xffff0000u));
                const unsigned l1 = rne_top16(xs[2*j+1] - __uint_as_float(e1 & 0xffff0000u));
                L.u[j] = pack_top16(l1, l0);
            }
            ah[mt] = H.v; al[mt] = L.v;
        }
        #pragma unroll
        for (int nb = 0; nb < 8; ++nb) {
            const bf16x8 bh = *(const bf16x8*)&sW[((kk * 8 + nb) * 64 + lane) * 8];
            const bf16x8 bl = *(const bf16x8*)&sW[16384 + ((kk * 8 + nb) * 64 + lane) * 8];
            #pragma unroll
            for (int mt = 0; mt < 2; ++mt) {
                acc[mt][nb] = MFMA(al[mt], bh, acc[mt][nb]);
                acc[mt][nb] = MFMA(ah[mt], bl, acc[mt][nb]);
                acc[mt][nb] = MFMA(ah[mt], bh, acc[mt][nb]);
            }
        }
    }

    // ---- esrc / edst: per-row dot with a_src / a_dst, reduce over 16 lanes ----
    float av[8], bv[8];
    #pragma unroll
    for (int nb = 0; nb < 8; ++nb) {
        av[nb] = a[nb * 16 + (lane & 15)];
        bv[nb] = a[FD + nb * 16 + (lane & 15)];
    }
    #pragma unroll
    for (int mt = 0; mt < 2; ++mt)
        #pragma unroll
        for (int r = 0; r < 4; ++r) {
            float ps = 0.f, pd = 0.f;
            #pragma unroll
            for (int nb = 0; nb < 8; ++nb) {
                ps += acc[mt][nb][r] * av[nb];
                pd += acc[mt][nb][r] * bv[nb];
            }
            #pragma unroll
            for (int off = 1; off <= 8; off <<= 1) {
                ps += __shfl_xor(ps, off);
                pd += __shfl_xor(pd, off);
            }
            if ((lane & 15) == 0) {
                const int row = g * NN + i0r + w * 32 + mt * 16 + (lane >> 4) * 4 + r;
                esrc[row] = ps;
                edst[row] = pd;
            }
        }

    // ---- transpose Wh -> swizzled bf16 hi/lo, two 4-nb passes (reuse sW) ----
    unsigned short* sTh = sW;            // 8192 shorts
    unsigned short* sTl = sW + 8192;     // 8192 shorts
    const size_t gbase = (size_t)g * 65536 + (size_t)jt * 16384;
    const int ib = 4 * ((lane >> 4) & 1);

    for (int ph = 0; ph < 2; ++ph) {
        __syncthreads();
        #pragma unroll
        for (int mt = 0; mt < 2; ++mt) {
            const int lp2 = (lane & 15) + 16 * (mt * 2 + (lane >> 5));
            #pragma unroll
            for (int nbp = 0; nbp < 4; ++nbp) {
                const int nb = ph * 4 + nbp;
                const int off = ((w * 4 + nbp) * 64 + lp2) * 8 + ib;
                const unsigned u0 = __float_as_uint(acc[mt][nb][0]);
                const unsigned u1 = __float_as_uint(acc[mt][nb][1]);
                const unsigned u2 = __float_as_uint(acc[mt][nb][2]);
                const unsigned u3 = __float_as_uint(acc[mt][nb][3]);
                *(uint2*)&sTh[off] = make_uint2(pack_top16(u1, u0), pack_top16(u3, u2));
                const unsigned l0 = rne_top16(acc[mt][nb][0] - __uint_as_float(u0 & 0xffff0000u));
                const unsigned l1 = rne_top16(acc[mt][nb][1] - __uint_as_float(u1 & 0xffff0000u));
                const unsigned l2 = rne_top16(acc[mt][nb][2] - __uint_as_float(u2 & 0xffff0000u));
                const unsigned l3 = rne_top16(acc[mt][nb][3] - __uint_as_float(u3 & 0xffff0000u));
                *(uint2*)&sTl[off] = make_uint2(pack_top16(l1, l0), pack_top16(l3, l2));
            }
        }
        __syncthreads();
        for (int q = t; q < 1024; q += 256) {
            const int qw = q >> 8, qr = q & 255;
            const size_t go = gbase + (size_t)(qw * 8 + ph * 4) * 512 + qr * 8;
            *(float4*)&whtHi[go] = *(const float4*)&sTh[q * 8];
            *(float4*)&whtLo[go] = *(const float4*)&sTl[q * 8];
        }
    }
}

// ---------------------------------------------------------------------------
// attn: block (g, it): 64 rows, grid 1024 (4 blocks/CU).
// m-hat = lrelu(esrc + max(edst)) upper bound (softmax shift-invariant;
// masked -> exp(-9e15 - mhat) == 0 exactly). P: single RNE bf16; lsum is
// accumulated from the ROUNDED p so normalization cancels rounding error.
// 2 MFMAs per product (P*WhHi + P*WhLo). Mask row in 16 SGPR-able registers.
// LDS ~34.8 KB -> 4 blocks/CU.
// ---------------------------------------------------------------------------
__global__ __launch_bounds__(256, 4) void attn_kernel(
    const unsigned short* __restrict__ whtHi, const unsigned short* __restrict__ whtLo,
    const float* __restrict__ esrc, const float* __restrict__ edst,
    const unsigned* __restrict__ mask, float* __restrict__ out)
{
    __shared__ __attribute__((aligned(16))) float eds[NN];            // 2 KB
    __shared__ __attribute__((aligned(16))) unsigned short cHi[8192]; // 16 KB
    __shared__ __attribute__((aligned(16))) unsigned short cLo[8192]; // 16 KB
    __shared__ float redS[4];

    const int bid = blockIdx.x;
    const int xcd = bid & 7, slot = bid >> 3;
    const int g = xcd + 8 * (slot >> 3);
    const int it = slot & 7;
    const int t = threadIdx.x, lane = t & 63, w = t >> 6;
    const int i0 = it * 64;
    const int q8 = (lane >> 4) * 8;

    const float e0 = edst[g * NN + t], e1 = edst[g * NN + 256 + t];
    eds[t] = e0; eds[t + 256] = e1;
    float mx = fmaxf(e0, e1);
    #pragma unroll
    for (int off = 1; off < 64; off <<= 1) mx = fmaxf(mx, __shfl_xor(mx, off));
    if (lane == 0) redS[w] = mx;

    const int rloc = w * 16 + (lane & 15);        // local row in [0,64)
    const float s0 = esrc[g * NN + i0 + rloc];
    unsigned mrow[16];
    *(uint4*)&mrow[0]  = *(const uint4*)&mask[(i0 + rloc) * 16];
    *(uint4*)&mrow[4]  = *(const uint4*)&mask[(i0 + rloc) * 16 + 4];
    *(uint4*)&mrow[8]  = *(const uint4*)&mask[(i0 + rloc) * 16 + 8];
    *(uint4*)&mrow[12] = *(const uint4*)&mask[(i0 + rloc) * 16 + 12];
    __syncthreads();
    const float maxE = fmaxf(fmaxf(redS[0], redS[1]), fmaxf(redS[2], redS[3]));
    const float mh = LRELU(s0 + maxE);

    f32x4 acc[8];
    #pragma unroll
    for (int nb = 0; nb < 8; ++nb) acc[nb] = (f32x4){0.f, 0.f, 0.f, 0.f};
    float lsum = 0.f;

    for (int c2 = 0; c2 < 8; ++c2) {
        __syncthreads();
        const size_t gb = (size_t)g * 65536 + (size_t)c2 * 8192;   // shorts
        for (int q = t; q < 1024; q += 256) {
            gload16(&whtHi[gb + q * 8], &cHi[q * 8]);
            gload16(&whtLo[gb + q * 8], &cLo[q * 8]);
        }
        __syncthreads();
        #pragma unroll
        for (int kl = 0; kl < 2; ++kl) {
            const int kk = c2 * 2 + kl;
            const float* ep = &eds[kk * 32 + q8];
            const float4 ed0 = *(const float4*)ep;
            const float4 ed1 = *(const float4*)(ep + 4);
            const float ev[8] = {ed0.x, ed0.y, ed0.z, ed0.w, ed1.x, ed1.y, ed1.z, ed1.w};
            const unsigned mw = mrow[kk] >> q8;

            union { bf16x8 v; unsigned u[4]; } H;
            unsigned uh[8];
            #pragma unroll
            for (int i = 0; i < 8; ++i) {
                float x = s0 + ev[i];
                x = LRELU(x);
                x = ((mw >> i) & 1u) ? x : NEG_BIG;
                const float p = __expf(x - mh);
                const unsigned r = rne_top16(p);
                lsum += __uint_as_float(r & 0xffff0000u);   // sum of ROUNDED p
                uh[i] = r;
            }
            #pragma unroll
            for (int j = 0; j < 4; ++j) H.u[j] = pack_top16(uh[2*j+1], uh[2*j]);

            #pragma unroll
            for (int nb = 0; nb < 8; ++nb) {
                const bf16x8 bl = *(const bf16x8*)&cLo[((kl * 8 + nb) * 64 + lane) * 8];
                const bf16x8 bh = *(const bf16x8*)&cHi[((kl * 8 + nb) * 64 + lane) * 8];
                acc[nb] = MFMA(H.v, bl, acc[nb]);
                acc[nb] = MFMA(H.v, bh, acc[nb]);
            }
        }
    }

    lsum += __shfl_xor(lsum, 16);
    lsum += __shfl_xor(lsum, 32);

    #pragma unroll
    for (int r = 0; r < 4; ++r) {
        const int rr = (lane >> 4) * 4 + r;            // row within 16-tile
        const float rl = 1.0f / __shfl(lsum, rr);
        const int row = g * NN + i0 + w * 16 + rr;
        #pragma unroll
        for (int nb = 0; nb < 8; ++nb)
            out[row * FD + nb * 16 + (lane & 15)] = acc[nb][r] * rl;
    }
}

// ---------------------------------------------------------------------------
extern "C" void kernel_launch(void* const* d_in, const int* in_sizes, int n_in,
                              void* d_out, int out_size, void* d_ws, size_t ws_size,
                              hipStream_t stream) {
    const float* h   = (const float*)d_in[0];
    const int*   adj = (const int*)d_in[1];
    const float* W   = (const float*)d_in[2];
    const float* a   = (const float*)d_in[3];
    float* out = (float*)d_out;

    unsigned short* whtHi = (unsigned short*)d_ws;                       // 16.78 MB
    unsigned short* whtLo = whtHi + (size_t)GN * 65536;                  // 16.78 MB
    float* esrc = (float*)(whtLo + (size_t)GN * 65536);                  // 256 KB
    float* edst = esrc + GN * NN;                                        // 256 KB
    unsigned* mask = (unsigned*)(edst + GN * NN);                        // 32 KB
    unsigned short* wsHi = (unsigned short*)(mask + 8192);               // 32 KB
    unsigned short* wsLo = wsHi + 16384;                                 // 32 KB

    prep_kernel<<<64, 256, 0, stream>>>(adj, W, mask, wsHi, wsLo);
    whb_kernel<<<512, 256, 0, stream>>>(h, a, wsHi, wsLo, whtHi, whtLo, esrc, edst);
    attn_kernel<<<1024, 256, 0, stream>>>(whtHi, whtLo, esrc, edst, mask, out);
}